// Round 1
// baseline (94.214 us; speedup 1.0000x reference)
//
#include <hip/hip_runtime.h>

#define DEV static __device__ __forceinline__

// DPP move: returns src shuffled per CTRL; out-of-range source lanes -> 0 (bound_ctrl)
template<int CTRL>
DEV float dpp_movf(float v) {
  return __int_as_float(__builtin_amdgcn_update_dpp(
      0, __float_as_int(v), CTRL, 0xF, 0xF, true));
}

// ds_swizzle xor16 within each 32-lane group: offset = (16<<10)|31 = 0x401F
DEV float swz_xor16(float v) {
  return __int_as_float(__builtin_amdgcn_ds_swizzle(__float_as_int(v), 0x401F));
}

// all-reduce sum over the 32-lane group (each lane ends with the full sum)
DEV float red32(float v) {
  v += dpp_movf<0xB1>(v);   // quad_perm [1,0,3,2]  == xor1
  v += dpp_movf<0x4E>(v);   // quad_perm [2,3,0,1]  == xor2
  v += dpp_movf<0x141>(v);  // row_half_mirror      == xor7 (acts as xor4, quads uniform)
  v += dpp_movf<0x140>(v);  // row_mirror           == xor15 (acts as xor8, 8-groups uniform)
  v += swz_xor16(v);        // xor16 within 32-lane group
  return v;
}

// gelu (tanh form): x * sigmoid(1.5957691216*(x + 0.044715 x^3)); |err| < ~1e-3
DEV float gelu_f(float x) {
  float x2 = x * x;
  float inner = x * __builtin_fmaf(0.044715f, x2, 1.0f);
  float e = __expf(-1.5957691216f * inner);
  return x * __builtin_amdgcn_rcpf(1.0f + e);
}

__global__ void __launch_bounds__(256) gmlp_fused(
    const float* __restrict__ x,
    const float* __restrict__ ln1_g, const float* __restrict__ ln1_b,
    const float* __restrict__ W1, const float* __restrict__ b1,
    const float* __restrict__ sgu_g, const float* __restrict__ sgu_b,
    const float* __restrict__ conv_w, const float* __restrict__ conv_b,
    const float* __restrict__ W2, const float* __restrict__ b2,
    float* __restrict__ out, int nsamp)
{
  const int pos = threadIdx.x & 31;   // position within sample (last axis)
  const int grp = threadIdx.x >> 5;   // sample-group within block
  const int gpb = blockDim.x >> 5;    // groups per block (8)

  // LN affine params are indexed by position -> loop-invariant per thread
  const float g1 = ln1_g[pos], be1 = ln1_b[pos];
  const float g2 = sgu_g[pos], be2 = sgu_b[pos];
  // conv zero-pad boundary masks
  const bool pm1 = pos >= 1, pm2 = pos >= 2, pp1 = pos <= 30, pp2 = pos <= 29;

  for (int s = blockIdx.x * gpb + grp; s < nsamp; s += gridDim.x * gpb) {
    const float* xs = x + (size_t)s * 256 + pos;
    float res[8], h[8];
#pragma unroll
    for (int c = 0; c < 8; ++c) res[c] = xs[c * 32];

    // ---- LN1: per channel, reduce over 32 positions (lanes) ----
#pragma unroll
    for (int c = 0; c < 8; ++c) {
      float s1 = red32(res[c]);
      float s2 = red32(res[c] * res[c]);
      float mu = s1 * 0.03125f;
      float var = __builtin_fmaf(s2, 0.03125f, -mu * mu);
      float rs = __builtin_amdgcn_rsqf(var + 1e-5f);
      h[c] = __builtin_fmaf((res[c] - mu) * rs, g1, be1);
    }

    // ---- channel-mix matmul (8x8) + exact-ish gelu, all lane-local ----
    float h2[8];
#pragma unroll
    for (int o = 0; o < 8; ++o) {
      float acc = b1[o];
#pragma unroll
      for (int c = 0; c < 8; ++c)
        acc = __builtin_fmaf(h[c], W1[o * 8 + c], acc);
      h2[o] = gelu_f(acc);
    }

    // ---- SGU: LN2 on v = h2[4..7] ----
    float vln[4];
#pragma unroll
    for (int c = 0; c < 4; ++c) {
      float val = h2[4 + c];
      float s1 = red32(val);
      float s2 = red32(val * val);
      float mu = s1 * 0.03125f;
      float var = __builtin_fmaf(s2, 0.03125f, -mu * mu);
      float rs = __builtin_amdgcn_rsqf(var + 1e-5f);
      vln[c] = __builtin_fmaf((val - mu) * rs, g2, be2);
    }

    // ---- conv taps: shifted copies via DPP wave shifts + boundary masks ----
    // wave_shr1 (0x138): lane l <- l-1 ; wave_shl1 (0x130): lane l <- l+1
    // cross-sample leakage at the 32-lane boundary is killed by the pos masks.
    float cm1[4], cm2[4], cp1[4], cp2[4];
#pragma unroll
    for (int c = 0; c < 4; ++c) {
      float a  = dpp_movf<0x138>(vln[c]); a  = pm1 ? a  : 0.0f; cm1[c] = a;
      float b_ = dpp_movf<0x138>(a);      b_ = pm2 ? b_ : 0.0f; cm2[c] = b_;
      float d  = dpp_movf<0x130>(vln[c]); d  = pp1 ? d  : 0.0f; cp1[c] = d;
      float e  = dpp_movf<0x130>(d);      e  = pp2 ? e  : 0.0f; cp2[c] = e;
    }

    // ---- conv (4 out ch, 4 in ch, 5 taps, correlation) + bias, then gate ----
    float gte[4];
#pragma unroll
    for (int o = 0; o < 4; ++o) {
      float acc = conv_b[o];
#pragma unroll
      for (int c = 0; c < 4; ++c) {
        const float* w = conv_w + (o * 4 + c) * 5;
        acc = __builtin_fmaf(cm2[c], w[0], acc);
        acc = __builtin_fmaf(cm1[c], w[1], acc);
        acc = __builtin_fmaf(vln[c], w[2], acc);
        acc = __builtin_fmaf(cp1[c], w[3], acc);
        acc = __builtin_fmaf(cp2[c], w[4], acc);
      }
      gte[o] = h2[o] * acc;   // u * v
    }

    // ---- out matmul (4->8) + gelu + residual, store ----
    float* os = out + (size_t)s * 256 + pos;
#pragma unroll
    for (int o = 0; o < 8; ++o) {
      float acc = b2[o];
#pragma unroll
      for (int c = 0; c < 4; ++c)
        acc = __builtin_fmaf(gte[c], W2[o * 4 + c], acc);
      os[o * 32] = gelu_f(acc) + res[o];
    }
  }
}

extern "C" void kernel_launch(void* const* d_in, const int* in_sizes, int n_in,
                              void* d_out, int out_size, void* d_ws, size_t ws_size,
                              hipStream_t stream) {
  const float* x      = (const float*)d_in[0];
  const float* ln1_g  = (const float*)d_in[1];
  const float* ln1_b  = (const float*)d_in[2];
  const float* W1     = (const float*)d_in[3];
  const float* b1     = (const float*)d_in[4];
  const float* sgu_g  = (const float*)d_in[5];
  const float* sgu_b  = (const float*)d_in[6];
  const float* conv_w = (const float*)d_in[7];
  const float* conv_b = (const float*)d_in[8];
  const float* W2     = (const float*)d_in[9];
  const float* b2     = (const float*)d_in[10];
  float* out = (float*)d_out;

  int nsamp = in_sizes[0] / 256;          // 131072 samples of 8*32
  int groups_needed = (nsamp + 7) / 8;    // 8 sample-groups per 256-thread block
  int nblocks = groups_needed < 4096 ? groups_needed : 4096;
  if (nblocks < 1) nblocks = 1;

  hipLaunchKernelGGL(gmlp_fused, dim3(nblocks), dim3(256), 0, stream,
                     x, ln1_g, ln1_b, W1, b1, sgu_g, sgu_b,
                     conv_w, conv_b, W2, b2, out, nsamp);
}

// Round 3
// 70.420 us; speedup vs baseline: 1.3379x; 1.3379x over previous
//
#include <hip/hip_runtime.h>

typedef float v2f __attribute__((ext_vector_type(2)));

#define DEV static __device__ __forceinline__

// ---- four independent 32-lane butterfly all-reduces, interleaved ----
// v_add_f32_dpp has a HW hazard: VALU write -> DPP read of same VGPR needs 2
// wait states. Interleaving 4 independent chains gives each register 3
// intervening instructions between its write and next DPP read, so no nops
// are needed inside; s_nop 1 guards the block entry (fresh val*val operands).
#define RED_ST(ctrl) \
  "v_add_f32_dpp %0, %0, %0 " ctrl " row_mask:0xf bank_mask:0xf\n\t" \
  "v_add_f32_dpp %1, %1, %1 " ctrl " row_mask:0xf bank_mask:0xf\n\t" \
  "v_add_f32_dpp %2, %2, %2 " ctrl " row_mask:0xf bank_mask:0xf\n\t" \
  "v_add_f32_dpp %3, %3, %3 " ctrl " row_mask:0xf bank_mask:0xf\n\t"

DEV float swz_xor16(float v) {
  return __int_as_float(__builtin_amdgcn_ds_swizzle(__float_as_int(v), 0x401F));
}

DEV void red32x4(float& a, float& b, float& c, float& d) {
  asm("s_nop 1\n\t"
      RED_ST("quad_perm:[1,0,3,2]")   // xor1
      RED_ST("quad_perm:[2,3,0,1]")   // xor2
      RED_ST("row_half_mirror")       // xor4-equiv (quads already uniform)
      RED_ST("row_mirror")            // xor8-equiv (8-groups uniform)
      : "+v"(a), "+v"(b), "+v"(c), "+v"(d));
  a += swz_xor16(a);                  // xor16 crosses the 16-lane rows
  b += swz_xor16(b);
  c += swz_xor16(c);
  d += swz_xor16(d);
}

// DPP move with bound_ctrl (OOB -> 0); compiler-managed hazards.
template<int CTRL>
DEV float dpp_movf(float v) {
  return __int_as_float(__builtin_amdgcn_update_dpp(
      0, __float_as_int(v), CTRL, 0xF, 0xF, true));
}

// packed gelu (tanh form): x*sigmoid(1.5957691*(x+0.044715x^3));
// z = -1.5957691216*log2(e) = -2.3022081; |err| < ~1e-3 << 0.4125 threshold
DEV v2f gelu2(v2f x) {
  v2f x2 = x * x;
  v2f t  = x * (x2 * 0.044715f + 1.0f);
  v2f z  = t * -2.3022081f;
  v2f e  = { __builtin_amdgcn_exp2f(z.x), __builtin_amdgcn_exp2f(z.y) };
  v2f den = e + 1.0f;
  v2f r  = { __builtin_amdgcn_rcpf(den.x), __builtin_amdgcn_rcpf(den.y) };
  return x * r;
}

// packed layernorm over the 32 lanes for a channel-pair
DEV v2f ln_pair(v2f val, v2f gv, v2f bv) {
  v2f sq = val * val;
  float s1a = val.x, s1b = val.y, s2a = sq.x, s2b = sq.y;
  red32x4(s1a, s1b, s2a, s2b);
  v2f s1 = { s1a, s1b }, s2 = { s2a, s2b };
  v2f mu  = s1 * 0.03125f;
  v2f var = s2 * 0.03125f - mu * mu;
  v2f ve  = var + 1e-5f;
  v2f rs  = { __builtin_amdgcn_rsqf(ve.x), __builtin_amdgcn_rsqf(ve.y) };
  v2f A = rs * gv;
  v2f B = bv - mu * A;
  return val * A + B;
}

__global__ void __launch_bounds__(256) gmlp_fused(
    const float* __restrict__ x,
    const float* __restrict__ ln1_g, const float* __restrict__ ln1_b,
    const float* __restrict__ W1, const float* __restrict__ b1,
    const float* __restrict__ sgu_g, const float* __restrict__ sgu_b,
    const float* __restrict__ conv_w, const float* __restrict__ conv_b,
    const float* __restrict__ W2, const float* __restrict__ b2,
    float* __restrict__ out, int nsamp)
{
  const int pos = threadIdx.x & 31;
  const int grp = threadIdx.x >> 5;
  const int gpb = blockDim.x >> 5;

  const float g1 = ln1_g[pos], be1 = ln1_b[pos];
  const float g2 = sgu_g[pos], be2 = sgu_b[pos];
  const v2f g1v = { g1, g1 }, b1v = { be1, be1 };
  const v2f g2v = { g2, g2 }, b2v = { be2, be2 };

  // conv zero-pad boundary masks as packed float multipliers
  const float fm1 = (pos >= 1) ? 1.0f : 0.0f;
  const float fm2 = (pos >= 2) ? 1.0f : 0.0f;
  const float fp1 = (pos <= 30) ? 1.0f : 0.0f;
  const float fp2 = (pos <= 29) ? 1.0f : 0.0f;
  const v2f mm1 = { fm1, fm1 }, mm2 = { fm2, fm2 };
  const v2f mp1 = { fp1, fp1 }, mp2 = { fp2, fp2 };

  const v2f* __restrict__ W1v = (const v2f*)W1;   // W1v[o*4+p]
  const v2f* __restrict__ W2v = (const v2f*)W2;   // W2v[o*2+p]

  for (int s = blockIdx.x * gpb + grp; s < nsamp; s += gridDim.x * gpb) {
    const float* xs = x + (size_t)s * 256 + pos;

    v2f res2[4];
#pragma unroll
    for (int p = 0; p < 4; ++p) res2[p] = v2f{ xs[(2*p)*32], xs[(2*p+1)*32] };

    // ---- LN1 over positions, per channel-pair ----
    v2f h[4];
#pragma unroll
    for (int p = 0; p < 4; ++p) h[p] = ln_pair(res2[p], g1v, b1v);

    // ---- channel-mix matmul (8x8) packed + bias ----
    float uo[8];
#pragma unroll
    for (int o = 0; o < 8; ++o) {
      v2f acc = h[0] * W1v[o*4 + 0];
      acc = h[1] * W1v[o*4 + 1] + acc;
      acc = h[2] * W1v[o*4 + 2] + acc;
      acc = h[3] * W1v[o*4 + 3] + acc;
      uo[o] = acc.x + acc.y + b1[o];
    }
    v2f t01 = gelu2(v2f{ uo[0], uo[1] });
    v2f t23 = gelu2(v2f{ uo[2], uo[3] });
    v2f t45 = gelu2(v2f{ uo[4], uo[5] });
    v2f t67 = gelu2(v2f{ uo[6], uo[7] });

    // ---- SGU: LN2 on v = channels 4..7 ----
    v2f vl[2];
    vl[0] = ln_pair(t45, g2v, b2v);
    vl[1] = ln_pair(t67, g2v, b2v);

    // ---- conv taps via DPP wave shifts, masked ----
    v2f cm1[2], cm2[2], cp1[2], cp2[2];
#pragma unroll
    for (int p = 0; p < 2; ++p) {
      v2f a = v2f{ dpp_movf<0x138>(vl[p].x),  dpp_movf<0x138>(vl[p].y)  } * mm1; // pos-1
      cm1[p] = a;
      cm2[p] = v2f{ dpp_movf<0x138>(a.x),     dpp_movf<0x138>(a.y)      } * mm2; // pos-2
      v2f d = v2f{ dpp_movf<0x130>(vl[p].x),  dpp_movf<0x130>(vl[p].y)  } * mp1; // pos+1
      cp1[p] = d;
      cp2[p] = v2f{ dpp_movf<0x130>(d.x),     dpp_movf<0x130>(d.y)      } * mp2; // pos+2
    }

    // ---- conv (4 out, 4 in, 5 taps) + bias, gate with u ----
    const float uu[4] = { t01.x, t01.y, t23.x, t23.y };
    float gte[4];
#pragma unroll
    for (int o = 0; o < 4; ++o) {
      float acc = conv_b[o];
#pragma unroll
      for (int c = 0; c < 4; ++c) {
        const float* w = conv_w + (o * 4 + c) * 5;
        float vm2 = (c & 1) ? cm2[c>>1].y : cm2[c>>1].x;
        float vm1 = (c & 1) ? cm1[c>>1].y : cm1[c>>1].x;
        float v0  = (c & 1) ? vl [c>>1].y : vl [c>>1].x;
        float vp1 = (c & 1) ? cp1[c>>1].y : cp1[c>>1].x;
        float vp2 = (c & 1) ? cp2[c>>1].y : cp2[c>>1].x;
        acc = __builtin_fmaf(vm2, w[0], acc);
        acc = __builtin_fmaf(vm1, w[1], acc);
        acc = __builtin_fmaf(v0,  w[2], acc);
        acc = __builtin_fmaf(vp1, w[3], acc);
        acc = __builtin_fmaf(vp2, w[4], acc);
      }
      gte[o] = uu[o] * acc;
    }

    // ---- out matmul (4->8) packed + gelu + residual ----
    const v2f gv0 = { gte[0], gte[1] }, gv1 = { gte[2], gte[3] };
    float oo[8];
#pragma unroll
    for (int o = 0; o < 8; ++o) {
      v2f acc = gv0 * W2v[o*2 + 0];
      acc = gv1 * W2v[o*2 + 1] + acc;
      oo[o] = acc.x + acc.y + b2[o];
    }
    float* os = out + (size_t)s * 256 + pos;
#pragma unroll
    for (int p = 0; p < 4; ++p) {
      v2f g = gelu2(v2f{ oo[2*p], oo[2*p+1] }) + res2[p];
      os[(2*p)*32]   = g.x;
      os[(2*p+1)*32] = g.y;
    }
  }
}

extern "C" void kernel_launch(void* const* d_in, const int* in_sizes, int n_in,
                              void* d_out, int out_size, void* d_ws, size_t ws_size,
                              hipStream_t stream) {
  const float* x      = (const float*)d_in[0];
  const float* ln1_g  = (const float*)d_in[1];
  const float* ln1_b  = (const float*)d_in[2];
  const float* W1     = (const float*)d_in[3];
  const float* b1     = (const float*)d_in[4];
  const float* sgu_g  = (const float*)d_in[5];
  const float* sgu_b  = (const float*)d_in[6];
  const float* conv_w = (const float*)d_in[7];
  const float* conv_b = (const float*)d_in[8];
  const float* W2     = (const float*)d_in[9];
  const float* b2     = (const float*)d_in[10];
  float* out = (float*)d_out;

  int nsamp = in_sizes[0] / 256;
  int groups_needed = (nsamp + 7) / 8;
  int nblocks = groups_needed < 4096 ? groups_needed : 4096;
  if (nblocks < 1) nblocks = 1;

  hipLaunchKernelGGL(gmlp_fused, dim3(nblocks), dim3(256), 0, stream,
                     x, ln1_g, ln1_b, W1, b1, sgu_g, sgu_b,
                     conv_w, conv_b, W2, b2, out, nsamp);
}